// Round 8
// baseline (149.771 us; speedup 1.0000x reference)
//
#include <hip/hip_runtime.h>
#include <hip/hip_bf16.h>
#include <math.h>

// CapsNet dynamic routing. R8: 8-wave routing + fused scans.
// - Block = (j, 4 batches), grid 640, 512 thr, LDS 146.6 KB -> 1 block/CU.
// - Phase A (all 8 waves) also accumulates f32 row-sums => round-0 s comes
//   free (and in f32), no scan0 needed.
// - Routing: wave pair (w, w+4) owns batch w&3, rows split 576/576. Rounds
//   fused: one row-scan does b-update dot + exp + s-accumulation (no cexp
//   array, no separate s-pass). 2 scans x 18 b128/lane total.
// - Per-lane s[16] partials reduced by a lane-bit fold (lane l ends with
//   m=l&15); cross-half combine = 17 floats via LDS + balanced barrier.
//   3 barriers total, all waves arrive together.
// - softmax max-free (|logit| small, f32 exp safe - verified R6/R7).
// - (512,2): VGPR cap 256; 1 block/CU anyway (LDS-bound), so no spill risk.
//
// u: [256][1152][8] f32; weight: [1152][10][8][16] f32; out: [256][10][16] f32

#define IC 1152
#define OC 10
#define NB 256

__device__ __forceinline__ float bf_lo(unsigned w) { return __uint_as_float(w << 16); }
__device__ __forceinline__ float bf_hi(unsigned w) { return __uint_as_float(w & 0xFFFF0000u); }
__device__ __forceinline__ unsigned pack2(float a, float b) {
    __hip_bfloat162 h = __float22bfloat162_rn(make_float2(a, b));
    return *(unsigned*)&h;
}

__global__ __launch_bounds__(512, 2)
void caps_route_kernel(const float* __restrict__ u,
                       const float* __restrict__ W,
                       float* __restrict__ out) {
    extern __shared__ unsigned smem_u[];
    unsigned* uh = smem_u;                     // 4 tiles * IC*8 dwords (147456 B)
    float* s0p   = (float*)(uh + 4 * IC * 8);  // [8 waves][4 batch][16 m] (2048 B)
    float* spart = s0p + 512;                  // [4 batch][2 half][20] (640 B)

    const int t    = threadIdx.x;
    const int bx   = blockIdx.x;
    const int lane = t & 63;
    const int wid  = t >> 6;

    // XCD-aware (j, batch-quad) mapping (xcd = bx & 7 heuristic).
    int x = bx & 7, sg = bx >> 3;
    int j, p;
    if (sg < 64) { j = x; p = sg; }
    else { int s2 = sg - 64; j = 8 + (x >> 2); p = ((x & 3) << 4) + s2; }
    const int bb = p * 4;  // batches bb..bb+3

    // ---- Phase A: uhat -> LDS bf16; also f32 row-sum partials (round-0 s) ----
    {
        const int q  = t & 3;            // logical m-quad
        const int i0 = t >> 2;           // 0..127
        const int pb = (((q >> 1) ^ ((i0 >> 2) & 1)) << 2) + ((q & 1) << 1);
        const float* uptr = u + (size_t)bb * (IC * 8);
        float4 z0 = {0.f,0.f,0.f,0.f}, z1 = z0, z2 = z0, z3 = z0;
#pragma unroll 3
        for (int k = 0; k < 9; ++k) {
            const int i = i0 + 128 * k;
            const float4* wrow = (const float4*)(W + ((size_t)(i * OC + j) << 7)) + q;
            const float* urow = uptr + i * 8;
            const float4 a0 = *(const float4*)(urow);
            const float4 a1 = *(const float4*)(urow + 4);
            const float4 b0 = *(const float4*)(urow + IC * 8);
            const float4 b1 = *(const float4*)(urow + IC * 8 + 4);
            const float4 c0 = *(const float4*)(urow + 2 * IC * 8);
            const float4 c1 = *(const float4*)(urow + 2 * IC * 8 + 4);
            const float4 d0 = *(const float4*)(urow + 3 * IC * 8);
            const float4 d1 = *(const float4*)(urow + 3 * IC * 8 + 4);
            float4 sA = {0.f,0.f,0.f,0.f}, sB = sA, sC = sA, sD = sA;
            float4 w4;
#define ST(n, fA, fB, fC, fD)                                             \
            w4 = wrow[(n) * 4];                                           \
            sA.x += (fA)*w4.x; sA.y += (fA)*w4.y; sA.z += (fA)*w4.z; sA.w += (fA)*w4.w; \
            sB.x += (fB)*w4.x; sB.y += (fB)*w4.y; sB.z += (fB)*w4.z; sB.w += (fB)*w4.w; \
            sC.x += (fC)*w4.x; sC.y += (fC)*w4.y; sC.z += (fC)*w4.z; sC.w += (fC)*w4.w; \
            sD.x += (fD)*w4.x; sD.y += (fD)*w4.y; sD.z += (fD)*w4.z; sD.w += (fD)*w4.w;
            ST(0, a0.x, b0.x, c0.x, d0.x) ST(1, a0.y, b0.y, c0.y, d0.y)
            ST(2, a0.z, b0.z, c0.z, d0.z) ST(3, a0.w, b0.w, c0.w, d0.w)
            ST(4, a1.x, b1.x, c1.x, d1.x) ST(5, a1.y, b1.y, c1.y, d1.y)
            ST(6, a1.z, b1.z, c1.z, d1.z) ST(7, a1.w, b1.w, c1.w, d1.w)
#undef ST
            const int dst = (i << 3) + pb;
            *(uint2*)&uh[dst]              = make_uint2(pack2(sA.x, sA.y), pack2(sA.z, sA.w));
            *(uint2*)&uh[IC * 8 + dst]     = make_uint2(pack2(sB.x, sB.y), pack2(sB.z, sB.w));
            *(uint2*)&uh[2 * IC * 8 + dst] = make_uint2(pack2(sC.x, sC.y), pack2(sC.z, sC.w));
            *(uint2*)&uh[3 * IC * 8 + dst] = make_uint2(pack2(sD.x, sD.y), pack2(sD.z, sD.w));
            z0.x += sA.x; z0.y += sA.y; z0.z += sA.z; z0.w += sA.w;
            z1.x += sB.x; z1.y += sB.y; z1.z += sB.z; z1.w += sB.w;
            z2.x += sC.x; z2.y += sC.y; z2.z += sC.z; z2.w += sC.w;
            z3.x += sD.x; z3.y += sD.y; z3.z += sD.z; z3.w += sD.w;
        }
        // wave-reduce row-sum partials over i0-in-wave (lane bits 2..5)
#pragma unroll
        for (int o = 4; o <= 32; o <<= 1) {
            z0.x += __shfl_xor(z0.x, o, 64); z0.y += __shfl_xor(z0.y, o, 64);
            z0.z += __shfl_xor(z0.z, o, 64); z0.w += __shfl_xor(z0.w, o, 64);
            z1.x += __shfl_xor(z1.x, o, 64); z1.y += __shfl_xor(z1.y, o, 64);
            z1.z += __shfl_xor(z1.z, o, 64); z1.w += __shfl_xor(z1.w, o, 64);
            z2.x += __shfl_xor(z2.x, o, 64); z2.y += __shfl_xor(z2.y, o, 64);
            z2.z += __shfl_xor(z2.z, o, 64); z2.w += __shfl_xor(z2.w, o, 64);
            z3.x += __shfl_xor(z3.x, o, 64); z3.y += __shfl_xor(z3.y, o, 64);
            z3.z += __shfl_xor(z3.z, o, 64); z3.w += __shfl_xor(z3.w, o, 64);
        }
        if (lane < 4) {  // lane == q here
            float* dstz = &s0p[wid * 64 + lane * 4];
            *(float4*)&dstz[0]  = z0;
            *(float4*)&dstz[16] = z1;
            *(float4*)&dstz[32] = z2;
            *(float4*)&dstz[48] = z3;
        }
    }

    __syncthreads();  // B0: uhat + s0 partials ready

    // ---- Routing: wave pair (wid&3, +4) = batch; halves split rows ----
    const int bt = wid & 3;
    const int hf = wid >> 2;
    const unsigned* uhT = uh + bt * (IC * 8);
    const int m16 = lane & 15;
    const bool eB = ((lane >> 2) & 1) != 0;   // phys-half swap for rows lane+64k
    const int base = hf * 576 + lane;

    // v0 from Phase-A f32 partials (c uniform = 1/IC)
    float sm = 0.f;
#pragma unroll
    for (int w = 0; w < 8; ++w) sm += s0p[w * 64 + bt * 16 + m16];
    sm *= (1.0f / (float)IC);
    float p2 = sm * sm;
#pragma unroll
    for (int o = 8; o >= 1; o >>= 1) p2 += __shfl_xor(p2, o, 16);
    float sc = p2 / ((1.0f + p2) * sqrtf(p2 + 1e-8f));
    float vm = sm * sc;

    float vp[16];  // v in this lane's PHYS dword order
    auto bcast_swap = [&]() {
        float vL[16];
#pragma unroll
        for (int m = 0; m < 16; ++m) vL[m] = __shfl(vm, m, 16);
#pragma unroll
        for (int d = 0; d < 16; ++d) vp[d] = eB ? vL[d ^ 8] : vL[d];
    };
    bcast_swap();

    float L[9];
#pragma unroll
    for (int k = 0; k < 9; ++k) L[k] = 0.f;

    // Fused scan: dot(v,row) -> L += dot -> e=exp(L) -> se, s[m] += e*row[m]
    auto scan = [&](bool isLast) {
        float sacc[16]; float se = 0.f;
#pragma unroll
        for (int d = 0; d < 16; ++d) sacc[d] = 0.f;
#pragma unroll
        for (int k = 0; k < 9; ++k) {
            const int i = base + 64 * k;
            const uint4 da = *(const uint4*)&uhT[(i << 3)];
            const uint4 db = *(const uint4*)&uhT[(i << 3) + 4];
            float f[16];
            f[0]=bf_lo(da.x);  f[1]=bf_hi(da.x);  f[2]=bf_lo(da.y);  f[3]=bf_hi(da.y);
            f[4]=bf_lo(da.z);  f[5]=bf_hi(da.z);  f[6]=bf_lo(da.w);  f[7]=bf_hi(da.w);
            f[8]=bf_lo(db.x);  f[9]=bf_hi(db.x);  f[10]=bf_lo(db.y); f[11]=bf_hi(db.y);
            f[12]=bf_lo(db.z); f[13]=bf_hi(db.z); f[14]=bf_lo(db.w); f[15]=bf_hi(db.w);
            float dot = 0.f;
#pragma unroll
            for (int d = 0; d < 16; ++d) dot += f[d] * vp[d];
            L[k] += dot;
            const float ev = __expf(L[k]);
            se += ev;
#pragma unroll
            for (int d = 0; d < 16; ++d) sacc[d] += ev * f[d];
        }
        // phys -> logical (eB lane-constant; one-time per scan)
        float c16[16];
#pragma unroll
        for (int d = 0; d < 16; ++d) c16[d] = eB ? sacc[d ^ 8] : sacc[d];
        // fold 16 -> 1, mapping m bits to lane bits: lane l ends with m=l&15
        float c8[8];
        { const bool q0 = (lane & 1) != 0;
#pragma unroll
          for (int i2 = 0; i2 < 8; ++i2) {
              const float e0 = c16[2*i2]   + __shfl_xor(c16[2*i2],   1, 64);
              const float e1 = c16[2*i2+1] + __shfl_xor(c16[2*i2+1], 1, 64);
              c8[i2] = q0 ? e1 : e0; } }
        float c4[4];
        { const bool q1 = (lane & 2) != 0;
#pragma unroll
          for (int i2 = 0; i2 < 4; ++i2) {
              const float e0 = c8[2*i2]   + __shfl_xor(c8[2*i2],   2, 64);
              const float e1 = c8[2*i2+1] + __shfl_xor(c8[2*i2+1], 2, 64);
              c4[i2] = q1 ? e1 : e0; } }
        float c2[2];
        { const bool q2 = (lane & 4) != 0;
#pragma unroll
          for (int i2 = 0; i2 < 2; ++i2) {
              const float e0 = c4[2*i2]   + __shfl_xor(c4[2*i2],   4, 64);
              const float e1 = c4[2*i2+1] + __shfl_xor(c4[2*i2+1], 4, 64);
              c2[i2] = q2 ? e1 : e0; } }
        float c1;
        { const bool q3 = (lane & 8) != 0;
          const float e0 = c2[0] + __shfl_xor(c2[0], 8, 64);
          const float e1 = c2[1] + __shfl_xor(c2[1], 8, 64);
          c1 = q3 ? e1 : e0; }
        c1 += __shfl_xor(c1, 16, 64);
        c1 += __shfl_xor(c1, 32, 64);
#pragma unroll
        for (int o = 32; o >= 1; o >>= 1) se += __shfl_xor(se, o, 64);
        // cross-half exchange
        if (lane < 16)       spart[bt * 40 + hf * 20 + lane] = c1;
        else if (lane == 16) spart[bt * 40 + hf * 20 + 16]   = se;
        __syncthreads();
        const float so  = spart[bt * 40 + (1 - hf) * 20 + m16];
        const float seo = spart[bt * 40 + (1 - hf) * 20 + 16];
        const float inv = 1.0f / (se + seo);
        sm = (c1 + so) * inv;
        p2 = sm * sm;
#pragma unroll
        for (int o = 8; o >= 1; o >>= 1) p2 += __shfl_xor(p2, o, 16);
        sc = p2 / ((1.0f + p2) * sqrtf(p2 + 1e-8f));
        vm = sm * sc;
        if (!isLast) bcast_swap();
    };

    scan(false);  // round 0 b-update + round 1 softmax/s -> v1
    scan(true);   // round 1 b-update + round 2 softmax/s -> v2 (output)

    if (hf == 0 && lane < 16)
        out[((size_t)(bb + bt) * OC + j) * 16 + lane] = vm;
}

extern "C" void kernel_launch(void* const* d_in, const int* in_sizes, int n_in,
                              void* d_out, int out_size, void* d_ws, size_t ws_size,
                              hipStream_t stream) {
    const float* u = (const float*)d_in[0];
    const float* W = (const float*)d_in[1];
    float* out = (float*)d_out;

    const size_t shmem = (size_t)(4 * IC * 8) * 4 + (512 + 160) * 4;  // 150144 B
    hipFuncSetAttribute((const void*)caps_route_kernel,
                        hipFuncAttributeMaxDynamicSharedMemorySize, (int)shmem);

    caps_route_kernel<<<(NB / 4) * OC, 512, shmem, stream>>>(u, W, out);
}

// Round 9
// 121.344 us; speedup vs baseline: 1.2343x; 1.2343x over previous
//
#include <hip/hip_runtime.h>
#include <hip/hip_bf16.h>
#include <math.h>

// CapsNet dynamic routing. R9 = R6 Phase A + R7 lean routing, even geometry.
// - Block = (j, 2 batches), grid 1280, 512 thr, LDS 77.1 KB -> 2 blocks/CU,
//   exactly 5 slots/CU (R7's grid 640 @ 1 block/CU had a 2.5/3-slot tail).
//   Co-resident blocks overlap Phase-A L2 streaming with routing VALU.
// - Routing: 2 waves per batch (wid&1 = batch, (wid>>1)&1 = row half, 576
//   rows/wave, 9/lane). R7's separate lean passes (exp pass -> s-pass ->
//   squash -> b-update) — NOT R8's fused scan (R8: VALU busy-cycles doubled,
//   22->43 us; fusion moved cheap LDS passes into redundant per-lane VALU).
// - One balanced barrier per round for the cross-half s/se combine; spart
//   double-buffered by round parity (R8 had a latent WAR race). Waves 4-7
//   mirror the 3 barriers (no exited-wave barrier semantics relied on).
// - __launch_bounds__(512,4): VGPR cap 128 == what 2 blocks x 8 waves needs.
//
// u: [256][1152][8] f32; weight: [1152][10][8][16] f32; out: [256][10][16] f32

#define IC 1152
#define OC 10
#define NB 256

__device__ __forceinline__ float bf_lo(unsigned w) { return __uint_as_float(w << 16); }
__device__ __forceinline__ float bf_hi(unsigned w) { return __uint_as_float(w & 0xFFFF0000u); }
__device__ __forceinline__ unsigned pack2(float a, float b) {
    __hip_bfloat162 h = __float22bfloat162_rn(make_float2(a, b));
    return *(unsigned*)&h;
}
__device__ __forceinline__ unsigned short pack1(float a) {
    __hip_bfloat16 h = __float2bfloat16(a);
    return *(unsigned short*)&h;
}

__global__ __launch_bounds__(512, 4)
void caps_route_kernel(const float* __restrict__ u,
                       const float* __restrict__ W,
                       float* __restrict__ out) {
    extern __shared__ unsigned smem_u[];
    unsigned* uh = smem_u;                                    // 2 tiles * IC*8 dwords (73728 B)
    unsigned short* ce = (unsigned short*)(uh + 2 * IC * 8);  // 2*IC bf16 (4608 B)
    float* spart = (float*)(ce + 2 * IC);                     // [2 parity][2 bt][2 hf][20] (640 B)

    const int t    = threadIdx.x;
    const int bx   = blockIdx.x;
    const int lane = t & 63;
    const int wid  = t >> 6;

    // XCD-aware (j, batch-pair) mapping (xcd = bx & 7 heuristic).
    int x = bx & 7, sg = bx >> 3;
    int j, p;
    if (sg < 128) { j = x; p = sg; }
    else { int s2 = sg - 128; j = 8 + (x >> 2); p = ((x & 3) << 5) + s2; }
    const int bb = p * 2;  // batches bb, bb+1

    // ---- Phase A (R6 verbatim): uhat[B][i][m] -> LDS bf16, half-XOR swizzle ----
    {
        const int q  = t & 3;            // logical m-quad
        const int i0 = t >> 2;           // 0..127; (i>>2)&1 k-independent
        const int pb = (((q >> 1) ^ ((i0 >> 2) & 1)) << 2) + ((q & 1) << 1);
        const float* u0p = u + (size_t)bb * (IC * 8);
#pragma unroll 3
        for (int k = 0; k < 9; ++k) {
            const int i = i0 + 128 * k;
            const float4* wrow = (const float4*)(W + ((size_t)(i * OC + j) << 7)) + q;
            const float4 ua0 = *(const float4*)(u0p + i * 8);
            const float4 ua1 = *(const float4*)(u0p + i * 8 + 4);
            const float4 ub0 = *(const float4*)(u0p + IC * 8 + i * 8);
            const float4 ub1 = *(const float4*)(u0p + IC * 8 + i * 8 + 4);
            float4 s0 = {0.f,0.f,0.f,0.f}, s1 = {0.f,0.f,0.f,0.f};
            float4 w4;
#define ST(ux, uy, n)                                                     \
            w4 = wrow[(n) * 4];                                           \
            s0.x += (ux)*w4.x; s0.y += (ux)*w4.y;                         \
            s0.z += (ux)*w4.z; s0.w += (ux)*w4.w;                         \
            s1.x += (uy)*w4.x; s1.y += (uy)*w4.y;                         \
            s1.z += (uy)*w4.z; s1.w += (uy)*w4.w;
            ST(ua0.x, ub0.x, 0) ST(ua0.y, ub0.y, 1) ST(ua0.z, ub0.z, 2) ST(ua0.w, ub0.w, 3)
            ST(ua1.x, ub1.x, 4) ST(ua1.y, ub1.y, 5) ST(ua1.z, ub1.z, 6) ST(ua1.w, ub1.w, 7)
#undef ST
            const int dst = (i << 3) + pb;
            *(uint2*)&uh[dst]          = make_uint2(pack2(s0.x, s0.y), pack2(s0.z, s0.w));
            *(uint2*)&uh[IC * 8 + dst] = make_uint2(pack2(s1.x, s1.y), pack2(s1.z, s1.w));
        }
    }

    __syncthreads();  // B0: uhat ready

    if (wid >= 4) {   // barrier mirrors for the 3 combine barriers, then done
        __syncthreads();
        __syncthreads();
        __syncthreads();
        return;
    }

    // ---- Routing: wave (bt, hf) owns batch bt's rows [hf*576, hf*576+576) ----
    const int bt = wid & 1;
    const int hf = (wid >> 1) & 1;
    const unsigned* uhT = uh + bt * (IC * 8);
    unsigned short* ceT = ce + bt * IC;
    const int rowbase = hf * 576;

    const int mq = lane & 3;          // s-pass m-quad
    const int h  = lane >> 2;         // s-pass row mod 16
    const int pbS = (((mq >> 1) ^ ((h >> 2) & 1)) << 2) + ((mq & 1) << 1);
    const bool eB = ((lane >> 2) & 1) != 0;  // b-update phys-half swap

    float L[9];
#pragma unroll
    for (int k = 0; k < 9; ++k) L[k] = 0.f;

    for (int r = 0; r < 3; ++r) {
        // ---- exp pass (r>0): L -> cexp (same-wave LDS, in-order DS) + se ----
        float se = 0.f;
        if (r > 0) {
#pragma unroll
            for (int k = 0; k < 9; ++k) {
                const float ev = __expf(L[k]);  // max-free: |logit| small (R6/R7)
                ceT[rowbase + lane + 64 * k] = pack1(ev);
                se += ev;
            }
#pragma unroll
            for (int o = 32; o >= 1; o >>= 1) se += __shfl_xor(se, o, 64);
        }

        // ---- s-pass: acc[mq-quad] over rows rowbase + 16k + h ----
        float4 acc = {0.f, 0.f, 0.f, 0.f};
        if (r == 0) {
#pragma unroll 6
            for (int k = 0; k < 36; ++k) {
                const int i = rowbase + 16 * k + h;
                const uint2 d = *(const uint2*)&uhT[(i << 3) + pbS];
                acc.x += bf_lo(d.x); acc.y += bf_hi(d.x);
                acc.z += bf_lo(d.y); acc.w += bf_hi(d.y);
            }
        } else {
#pragma unroll 6
            for (int k = 0; k < 36; ++k) {
                const int i = rowbase + 16 * k + h;
                const uint2 d = *(const uint2*)&uhT[(i << 3) + pbS];
                const float c = __uint_as_float(((unsigned)ceT[i]) << 16);
                acc.x += c * bf_lo(d.x); acc.y += c * bf_hi(d.x);
                acc.z += c * bf_lo(d.y); acc.w += c * bf_hi(d.y);
            }
        }
#pragma unroll
        for (int o = 4; o <= 32; o <<= 1) {   // reduce over h within wave
            acc.x += __shfl_xor(acc.x, o, 64);
            acc.y += __shfl_xor(acc.y, o, 64);
            acc.z += __shfl_xor(acc.z, o, 64);
            acc.w += __shfl_xor(acc.w, o, 64);
        }

        // ---- cross-half combine (parity-double-buffered spart) ----
        float* sp = spart + (r & 1) * 80 + bt * 40 + hf * 20;
        if (lane < 4) *(float4*)&sp[lane << 2] = acc;   // lane==mq, h==0
        if (r > 0 && lane == 4) sp[16] = se;
        __syncthreads();
        const float* so = spart + (r & 1) * 80 + bt * 40 + (1 - hf) * 20;
        const float4 oq = *(const float4*)&so[mq << 2];
        const float inv = (r == 0) ? (1.0f / (float)IC) : 1.0f / (se + so[16]);
        const float4 s4 = make_float4((acc.x + oq.x) * inv, (acc.y + oq.y) * inv,
                                      (acc.z + oq.z) * inv, (acc.w + oq.w) * inv);

        // ---- squash ----
        float p2 = s4.x*s4.x + s4.y*s4.y + s4.z*s4.z + s4.w*s4.w;
        p2 += __shfl_xor(p2, 1, 64);
        p2 += __shfl_xor(p2, 2, 64);   // sum over mq quads
        const float sc = p2 / ((1.0f + p2) * sqrtf(p2 + 1e-8f));
        const float4 vq = make_float4(s4.x * sc, s4.y * sc, s4.z * sc, s4.w * sc);

        if (r == 2) {
            if (hf == 0 && lane < 4)   // lanes 0..3 hold mq=lane (h==0)
                *(float4*)&out[((size_t)(bb + bt) * OC + j) * 16 + (lane << 2)] = vq;
        } else {
            // broadcast v quads via width-4 shuffles; pre-swap for phys order
            const float4 q0 = make_float4(__shfl(vq.x, 0, 4), __shfl(vq.y, 0, 4),
                                          __shfl(vq.z, 0, 4), __shfl(vq.w, 0, 4));
            const float4 q1 = make_float4(__shfl(vq.x, 1, 4), __shfl(vq.y, 1, 4),
                                          __shfl(vq.z, 1, 4), __shfl(vq.w, 1, 4));
            const float4 q2 = make_float4(__shfl(vq.x, 2, 4), __shfl(vq.y, 2, 4),
                                          __shfl(vq.z, 2, 4), __shfl(vq.w, 2, 4));
            const float4 q3 = make_float4(__shfl(vq.x, 3, 4), __shfl(vq.y, 3, 4),
                                          __shfl(vq.z, 3, 4), __shfl(vq.w, 3, 4));
            const float4 Qa0 = eB ? q2 : q0, Qa1 = eB ? q3 : q1;
            const float4 Qb0 = eB ? q0 : q2, Qb1 = eB ? q1 : q3;
            // ---- b-update: L[k] += v . uhat[rowbase + lane + 64k][:] ----
#pragma unroll 3
            for (int k = 0; k < 9; ++k) {
                const int i = rowbase + lane + 64 * k;
                const uint4 da = *(const uint4*)&uhT[i << 3];
                const uint4 db = *(const uint4*)&uhT[(i << 3) + 4];
                L[k] += bf_lo(da.x)*Qa0.x + bf_hi(da.x)*Qa0.y
                      + bf_lo(da.y)*Qa0.z + bf_hi(da.y)*Qa0.w
                      + bf_lo(da.z)*Qa1.x + bf_hi(da.z)*Qa1.y
                      + bf_lo(da.w)*Qa1.z + bf_hi(da.w)*Qa1.w
                      + bf_lo(db.x)*Qb0.x + bf_hi(db.x)*Qb0.y
                      + bf_lo(db.y)*Qb0.z + bf_hi(db.y)*Qb0.w
                      + bf_lo(db.z)*Qb1.x + bf_hi(db.z)*Qb1.y
                      + bf_lo(db.w)*Qb1.z + bf_hi(db.w)*Qb1.w;
            }
        }
    }
}

extern "C" void kernel_launch(void* const* d_in, const int* in_sizes, int n_in,
                              void* d_out, int out_size, void* d_ws, size_t ws_size,
                              hipStream_t stream) {
    const float* u = (const float*)d_in[0];
    const float* W = (const float*)d_in[1];
    float* out = (float*)d_out;

    const size_t shmem = (size_t)(2 * IC * 8) * 4 + (size_t)(2 * IC) * 2 + 160 * 4;  // 78976 B
    hipFuncSetAttribute((const void*)caps_route_kernel,
                        hipFuncAttributeMaxDynamicSharedMemorySize, (int)shmem);

    caps_route_kernel<<<(NB / 2) * OC, 512, shmem, stream>>>(u, W, out);
}